// Round 1
// baseline (301.425 us; speedup 1.0000x reference)
//
#include <hip/hip_runtime.h>
#include <stdint.h>

// Problem constants (fixed-shape problem)
#define SEQ    2048
#define DMODEL 2048
#define NHEAD  32
#define NKV    8
#define HDIM   64
#define NQKV   3072   // 2048 q + 512 k + 512 v

typedef __bf16 bf16x8 __attribute__((ext_vector_type(8)));
typedef float  f32x4  __attribute__((ext_vector_type(4)));

__device__ __forceinline__ ushort f2bf(float f){
  union { float f; uint32_t u; } a; a.f = f;
  uint32_t r = a.u + 0x7fffu + ((a.u >> 16) & 1u);
  return (ushort)(r >> 16);
}

__device__ __forceinline__ void gl_lds16(const void* g, void* l){
  __builtin_amdgcn_global_load_lds(
      (const __attribute__((address_space(1))) uint32_t*)g,
      (__attribute__((address_space(3))) uint32_t*)l, 16, 0, 0);
}

// ---------------- f32 -> bf16 convert (vector x4) ----------------
__global__ __launch_bounds__(256) void k_cvt(const float* __restrict__ src,
                                             ushort* __restrict__ dst, int n4){
  int i = blockIdx.x * 256 + threadIdx.x;
  if (i >= n4) return;
  float4 v = reinterpret_cast<const float4*>(src)[i];
  ushort4 o;
  o.x = f2bf(v.x); o.y = f2bf(v.y); o.z = f2bf(v.z); o.w = f2bf(v.w);
  reinterpret_cast<ushort4*>(dst)[i] = o;
}

// ---------------- GEMM: C[m][n] = sum_k A[m][k] * B[n][k] ----------------
// A: [M][K] bf16 row-major, B: [N][K] bf16 row-major ("B^T" form), C: [M][N] f32.
// 128x128 tile, BK=32, 4 waves (2x2), global_load_lds into linear LDS with
// XOR-swizzled source + matching swizzled ds_read (both-sides-or-neither).
__global__ __launch_bounds__(256) void k_gemm_bt(const ushort* __restrict__ A,
                                                 const ushort* __restrict__ B,
                                                 float* __restrict__ C,
                                                 int M, int N, int K){
  __shared__ ushort As[128*32];
  __shared__ ushort Bs[128*32];
  const int tid  = threadIdx.x;
  const int lane = tid & 63;
  const int wid  = tid >> 6;
  const int bm = blockIdx.y * 128;
  const int bn = blockIdx.x * 128;
  const int wr = wid >> 1, wc = wid & 1;
  const int l15 = lane & 15, u = lane >> 4;

  // staging: each wave fills two 1KB chunks (16 rows x 64B each) of As and Bs
  const int rA0 = wid*32 + (lane >> 2);        // local row, chunk 0
  const int rA1 = wid*32 + 16 + (lane >> 2);   // local row, chunk 1
  const int sl  = lane & 3;                    // 16B slot within 64B row
  const int cA0 = (sl ^ ((rA0 >> 1) & 3)) * 8; // pre-swizzled source col (shorts)
  const int cA1 = (sl ^ ((rA1 >> 1) & 3)) * 8;

  const ushort* Ab0 = A + (size_t)(bm + rA0) * K + cA0;
  const ushort* Ab1 = A + (size_t)(bm + rA1) * K + cA1;
  const ushort* Bb0 = B + (size_t)(bn + rA0) * K + cA0;
  const ushort* Bb1 = B + (size_t)(bn + rA1) * K + cA1;
  ushort* ldsA0 = As + wid*1024;
  ushort* ldsA1 = As + wid*1024 + 512;
  ushort* ldsB0 = Bs + wid*1024;
  ushort* ldsB1 = Bs + wid*1024 + 512;

  f32x4 acc[4][4] = {};

  for (int k0 = 0; k0 < K; k0 += 32){
    __syncthreads();                 // protect LDS from previous iteration's readers
    gl_lds16(Ab0 + k0, ldsA0);
    gl_lds16(Ab1 + k0, ldsA1);
    gl_lds16(Bb0 + k0, ldsB0);
    gl_lds16(Bb1 + k0, ldsB1);
    __syncthreads();                 // drains vmcnt(0): staged data visible

    bf16x8 af[4], bfr[4];
#pragma unroll
    for (int m = 0; m < 4; m++){
      int row = wr*64 + m*16 + l15;
      af[m] = *reinterpret_cast<const bf16x8*>(&As[row*32 + ((u ^ ((row>>1)&3)) * 8)]);
    }
#pragma unroll
    for (int n = 0; n < 4; n++){
      int row = wc*64 + n*16 + l15;
      bfr[n] = *reinterpret_cast<const bf16x8*>(&Bs[row*32 + ((u ^ ((row>>1)&3)) * 8)]);
    }
#pragma unroll
    for (int m = 0; m < 4; m++)
#pragma unroll
      for (int n = 0; n < 4; n++)
        acc[m][n] = __builtin_amdgcn_mfma_f32_16x16x32_bf16(af[m], bfr[n], acc[m][n], 0, 0, 0);
  }

  // epilogue: C/D layout col=lane&15, row=(lane>>4)*4+j
#pragma unroll
  for (int m = 0; m < 4; m++)
#pragma unroll
    for (int n = 0; n < 4; n++)
#pragma unroll
      for (int j = 0; j < 4; j++){
        int row = bm + wr*64 + m*16 + u*4 + j;
        int col = bn + wc*64 + n*16 + l15;
        C[(size_t)row * N + col] = acc[m][n][j];
      }
}

// ---------------- fused RMSNorm + RoPE + bf16 cast ----------------
// qkv: [SEQ][3072] f32.  Outputs: qb [SEQ][2048], kb [SEQ][512], vb [SEQ][512] bf16.
__global__ __launch_bounds__(256) void k_normrope(const float* __restrict__ qkv,
                                                  const float* __restrict__ cosp,
                                                  const float* __restrict__ sinp,
                                                  const float* __restrict__ qg,
                                                  const float* __restrict__ kg,
                                                  ushort* __restrict__ qb,
                                                  ushort* __restrict__ kb,
                                                  ushort* __restrict__ vb){
  const int s = blockIdx.x;
  const int tid = threadIdx.x, lane = tid & 63, wid = tid >> 6;
  const float* row = qkv + (size_t)s * NQKV;
  const float cs = cosp[s*HDIM + lane];
  const float sn = sinp[s*HDIM + lane];

  for (int hidx = wid; hidx < 40; hidx += 4){
    const bool isq = hidx < 32;
    const int col = isq ? hidx*64 : 2048 + (hidx-32)*64;
    float x = row[col + lane];
    float ss = x * x;
#pragma unroll
    for (int m = 1; m < 64; m <<= 1) ss += __shfl_xor(ss, m);
    float r = rsqrtf(ss * (1.0f/64.0f) + 1e-6f);
    float y = x * r * (isq ? qg : kg)[lane];
    // HF RoPE: out[d] = y[d]*cos[d] + (d<32 ? -y[d+32] : y[d-32])*sin[d]
    float p = __shfl_xor(y, 32);
    float out = y * cs + (lane < 32 ? -p : p) * sn;
    ushort o = f2bf(out);
    if (isq) qb[(size_t)s*2048 + hidx*64 + lane] = o;
    else     kb[(size_t)s*512 + (hidx-32)*64 + lane] = o;
  }
  // v passthrough (512 f32 per row -> bf16)
  float2 v2 = reinterpret_cast<const float2*>(row + 2560)[tid];
  ushort2 o2; o2.x = f2bf(v2.x); o2.y = f2bf(v2.y);
  reinterpret_cast<ushort2*>(vb + (size_t)s*512)[tid] = o2;
}

// ---------------- causal flash GQA attention ----------------
// grid: (32 q-blocks, 32 heads). block: 256 threads (4 waves x 16 q-rows).
// ctx out: [SEQ][2048] bf16 at [s][h*64+d].
__global__ __launch_bounds__(256) void k_attn(const ushort* __restrict__ qbuf,
                                              const ushort* __restrict__ kbuf,
                                              const ushort* __restrict__ vbuf,
                                              ushort* __restrict__ ctx){
  __shared__ ushort Klds[64*64];        // linear, XOR-swizzled content
  __shared__ ushort Vt[64*72];          // V^T [hd][key], padded stride 72
  __shared__ ushort Plds[4][16*72];     // per-wave P, padded stride 72

  const int qblk = blockIdx.x, h = blockIdx.y, g = h >> 2;
  const int tid = threadIdx.x, lane = tid & 63, wid = tid >> 6;
  const int l15 = lane & 15, u = lane >> 4;
  const int qrow0 = qblk*64 + wid*16;
  const int qmax  = qrow0 + 15;

  // Q fragments in registers (A-layout: row=lane&15, k=(lane>>4)*8 within chunk)
  bf16x8 qf[2];
#pragma unroll
  for (int kc = 0; kc < 2; kc++)
    qf[kc] = *reinterpret_cast<const bf16x8*>(
        qbuf + (size_t)(qrow0 + l15)*2048 + h*64 + kc*32 + u*8);

  f32x4 o[4] = {};
  float mrun[4], lrun[4];
#pragma unroll
  for (int j = 0; j < 4; j++){ mrun[j] = -1e30f; lrun[j] = 0.f; }

  // K staging params: 8 chunks of 1KB (8 rows x 128B); wave stages 2 chunks
  const int krow0 = wid*16 + (lane >> 3);
  const int krow1 = wid*16 + 8 + (lane >> 3);
  const int ksl   = lane & 7;
  const int kc0   = (ksl ^ (krow0 & 7)) * 8;   // pre-swizzled source col (shorts)
  const int kc1   = (ksl ^ (krow1 & 7)) * 8;

  for (int t = 0; t <= qblk; t++){
    __syncthreads();
    // stage K tile (64 keys x 64 hd) via global_load_lds, swizzled
    gl_lds16(kbuf + (size_t)(t*64 + krow0)*512 + g*64 + kc0, Klds + wid*1024);
    gl_lds16(kbuf + (size_t)(t*64 + krow1)*512 + g*64 + kc1, Klds + wid*1024 + 512);
    // stage V^T (reg-staged transpose)
#pragma unroll
    for (int i = 0; i < 4; i++){
      int qid = i*256 + tid;
      int r = qid >> 4, d4 = qid & 15;
      ushort4 v4 = *reinterpret_cast<const ushort4*>(
          vbuf + (size_t)(t*64 + r)*512 + g*64 + d4*4);
      Vt[(d4*4+0)*72 + r] = v4.x;
      Vt[(d4*4+1)*72 + r] = v4.y;
      Vt[(d4*4+2)*72 + r] = v4.z;
      Vt[(d4*4+3)*72 + r] = v4.w;
    }
    __syncthreads();

    // scores: S[q][key] = QK^T * 0.125, causal-masked
    f32x4 sc[4];
#pragma unroll
    for (int kb = 0; kb < 4; kb++){
      const int key0 = t*64 + kb*16;
      if (key0 > qmax){
#pragma unroll
        for (int j = 0; j < 4; j++) sc[kb][j] = -1e30f;
        continue;
      }
      const int keyl = kb*16 + l15;
      f32x4 a = {};
#pragma unroll
      for (int kc = 0; kc < 2; kc++){
        int slot = (kc*4 + u) ^ (keyl & 7);
        bf16x8 bfr = *reinterpret_cast<const bf16x8*>(&Klds[keyl*64 + slot*8]);
        a = __builtin_amdgcn_mfma_f32_16x16x32_bf16(qf[kc], bfr, a, 0, 0, 0);
      }
      const int key = key0 + l15;
#pragma unroll
      for (int j = 0; j < 4; j++){
        int qr = qrow0 + u*4 + j;
        sc[kb][j] = (key > qr) ? -1e30f : a[j] * 0.125f;
      }
    }

    // online softmax (rows owned by 16-lane groups; reduce via shfl_xor 1,2,4,8)
    float tm[4];
#pragma unroll
    for (int j = 0; j < 4; j++){
      float m0 = fmaxf(fmaxf(sc[0][j], sc[1][j]), fmaxf(sc[2][j], sc[3][j]));
#pragma unroll
      for (int msk = 1; msk < 16; msk <<= 1) m0 = fmaxf(m0, __shfl_xor(m0, msk));
      tm[j] = m0;
    }
    float alpha[4];
#pragma unroll
    for (int j = 0; j < 4; j++){
      float mn = fmaxf(mrun[j], tm[j]);
      alpha[j] = __expf(mrun[j] - mn);
      mrun[j] = mn;
    }
#pragma unroll
    for (int kb = 0; kb < 4; kb++)
#pragma unroll
      for (int j = 0; j < 4; j++)
        sc[kb][j] = __expf(sc[kb][j] - mrun[j]);
#pragma unroll
    for (int j = 0; j < 4; j++){
      float s0 = sc[0][j] + sc[1][j] + sc[2][j] + sc[3][j];
#pragma unroll
      for (int msk = 1; msk < 16; msk <<= 1) s0 += __shfl_xor(s0, msk);
      lrun[j] = lrun[j]*alpha[j] + s0;
    }
#pragma unroll
    for (int d0 = 0; d0 < 4; d0++)
#pragma unroll
      for (int j = 0; j < 4; j++) o[d0][j] *= alpha[j];

    // P -> bf16 -> wave-private LDS (D-layout write, A-layout read)
#pragma unroll
    for (int kb = 0; kb < 4; kb++)
#pragma unroll
      for (int j = 0; j < 4; j++)
        Plds[wid][(u*4+j)*72 + kb*16 + l15] = f2bf(sc[kb][j]);

    // O += P @ V  (A from Plds, B from Vt)
#pragma unroll
    for (int kc = 0; kc < 2; kc++){
      bf16x8 pa = *reinterpret_cast<const bf16x8*>(&Plds[wid][l15*72 + kc*32 + u*8]);
#pragma unroll
      for (int d0 = 0; d0 < 4; d0++){
        bf16x8 vb8 = *reinterpret_cast<const bf16x8*>(&Vt[(d0*16 + l15)*72 + kc*32 + u*8]);
        o[d0] = __builtin_amdgcn_mfma_f32_16x16x32_bf16(pa, vb8, o[d0], 0, 0, 0);
      }
    }
  }

  // epilogue: normalize and store ctx bf16
#pragma unroll
  for (int d0 = 0; d0 < 4; d0++)
#pragma unroll
    for (int j = 0; j < 4; j++){
      float val = o[d0][j] / lrun[j];
      ctx[(size_t)(qrow0 + u*4 + j)*2048 + h*64 + d0*16 + l15] = f2bf(val);
    }
}

// ---------------- launcher ----------------
extern "C" void kernel_launch(void* const* d_in, const int* in_sizes, int n_in,
                              void* d_out, int out_size, void* d_ws, size_t ws_size,
                              hipStream_t stream){
  const float* x    = (const float*)d_in[0];
  // d_in[1] = mask (unused; causal mask computed analytically)
  const float* cosp = (const float*)d_in[2];
  const float* sinp = (const float*)d_in[3];
  const float* wq   = (const float*)d_in[4];
  const float* wk   = (const float*)d_in[5];
  const float* wv   = (const float*)d_in[6];
  const float* wo   = (const float*)d_in[7];
  const float* qg   = (const float*)d_in[8];
  const float* kg   = (const float*)d_in[9];
  float* out = (float*)d_out;

  char* ws = (char*)d_ws;
  ushort* xb   = (ushort*)(ws);                    //  8 MB  x bf16
  ushort* wcat = (ushort*)(ws + 8388608);          // 12 MB  [wq;wk;wv] bf16 [3072][2048]
  ushort* wob  = (ushort*)(ws + 20971520);         //  8 MB  wo bf16
  float*  qkvf = (float* )(ws + 29360128);         // 24 MB  qkv f32 [2048][3072]
  ushort* qbuf = (ushort*)(ws + 54525952);         //  8 MB  q bf16 [2048][2048]
  ushort* kbuf = (ushort*)(ws + 62914560);         //  2 MB  k bf16 [2048][512]
  ushort* vbuf = (ushort*)(ws + 65011712);         //  2 MB  v bf16 [2048][512]
  ushort* ctxb = (ushort*)(ws + 67108864);         //  8 MB  ctx bf16 [2048][2048]
  // total 75,497,472 bytes

  k_cvt<<<4096, 256, 0, stream>>>(x,  xb,   1048576);
  k_cvt<<<4096, 256, 0, stream>>>(wq, wcat, 1048576);
  k_cvt<<<1024, 256, 0, stream>>>(wk, wcat + 2048*2048, 262144);
  k_cvt<<<1024, 256, 0, stream>>>(wv, wcat + 2560*2048, 262144);
  k_cvt<<<4096, 256, 0, stream>>>(wo, wob,  1048576);

  k_gemm_bt<<<dim3(24, 16), 256, 0, stream>>>(xb, wcat, qkvf, 2048, 3072, 2048);
  k_normrope<<<2048, 256, 0, stream>>>(qkvf, cosp, sinp, qg, kg, qbuf, kbuf, vbuf);
  k_attn<<<dim3(32, 32), 256, 0, stream>>>(qbuf, kbuf, vbuf, ctxb);
  k_gemm_bt<<<dim3(16, 16), 256, 0, stream>>>(ctxb, wob, out, 2048, 2048, 2048);
}

// Round 2
// 236.609 us; speedup vs baseline: 1.2739x; 1.2739x over previous
//
#include <hip/hip_runtime.h>
#include <stdint.h>

// Problem constants (fixed-shape problem)
#define SEQ    2048
#define DMODEL 2048
#define NHEAD  32
#define NKV    8
#define HDIM   64
#define NQKV   3072   // 2048 q + 512 k + 512 v

typedef __bf16 bf16x8 __attribute__((ext_vector_type(8)));
typedef float  f32x4  __attribute__((ext_vector_type(4)));

__device__ __forceinline__ ushort f2bf(float f){
  union { float f; uint32_t u; } a; a.f = f;
  uint32_t r = a.u + 0x7fffu + ((a.u >> 16) & 1u);
  return (ushort)(r >> 16);
}

__device__ __forceinline__ void gl_lds16(const void* g, void* l){
  __builtin_amdgcn_global_load_lds(
      (const __attribute__((address_space(1))) uint32_t*)g,
      (__attribute__((address_space(3))) uint32_t*)l, 16, 0, 0);
}

// ---------------- f32 -> bf16 convert (vector x4) ----------------
__global__ __launch_bounds__(256) void k_cvt(const float* __restrict__ src,
                                             ushort* __restrict__ dst, int n4){
  int i = blockIdx.x * 256 + threadIdx.x;
  if (i >= n4) return;
  float4 v = reinterpret_cast<const float4*>(src)[i];
  ushort4 o;
  o.x = f2bf(v.x); o.y = f2bf(v.y); o.z = f2bf(v.z); o.w = f2bf(v.w);
  reinterpret_cast<ushort4*>(dst)[i] = o;
}

// ---------------- GEMM: C[m][n] = sum_k A[m][k] * B[n][k] ----------------
// A: [M][K] bf16 row-major, B: [N][K] bf16 row-major ("B^T" form), C: [M][N] f32.
// 128x128 tile, BK=32, 4 waves (2x2), global_load_lds into linear LDS with
// XOR-swizzled source + matching swizzled ds_read (both-sides-or-neither).
__global__ __launch_bounds__(256) void k_gemm_bt(const ushort* __restrict__ A,
                                                 const ushort* __restrict__ B,
                                                 float* __restrict__ C,
                                                 int M, int N, int K){
  __shared__ ushort As[128*32];
  __shared__ ushort Bs[128*32];
  const int tid  = threadIdx.x;
  const int lane = tid & 63;
  const int wid  = tid >> 6;
  const int bm = blockIdx.y * 128;
  const int bn = blockIdx.x * 128;
  const int wr = wid >> 1, wc = wid & 1;
  const int l15 = lane & 15, u = lane >> 4;

  // staging: each wave fills two 1KB chunks (16 rows x 64B each) of As and Bs
  const int rA0 = wid*32 + (lane >> 2);        // local row, chunk 0
  const int rA1 = wid*32 + 16 + (lane >> 2);   // local row, chunk 1
  const int sl  = lane & 3;                    // 16B slot within 64B row
  const int cA0 = (sl ^ ((rA0 >> 1) & 3)) * 8; // pre-swizzled source col (shorts)
  const int cA1 = (sl ^ ((rA1 >> 1) & 3)) * 8;

  const ushort* Ab0 = A + (size_t)(bm + rA0) * K + cA0;
  const ushort* Ab1 = A + (size_t)(bm + rA1) * K + cA1;
  const ushort* Bb0 = B + (size_t)(bn + rA0) * K + cA0;
  const ushort* Bb1 = B + (size_t)(bn + rA1) * K + cA1;
  ushort* ldsA0 = As + wid*1024;
  ushort* ldsA1 = As + wid*1024 + 512;
  ushort* ldsB0 = Bs + wid*1024;
  ushort* ldsB1 = Bs + wid*1024 + 512;

  f32x4 acc[4][4] = {};

  for (int k0 = 0; k0 < K; k0 += 32){
    __syncthreads();                 // protect LDS from previous iteration's readers
    gl_lds16(Ab0 + k0, ldsA0);
    gl_lds16(Ab1 + k0, ldsA1);
    gl_lds16(Bb0 + k0, ldsB0);
    gl_lds16(Bb1 + k0, ldsB1);
    __syncthreads();                 // drains vmcnt(0): staged data visible

    bf16x8 af[4], bfr[4];
#pragma unroll
    for (int m = 0; m < 4; m++){
      int row = wr*64 + m*16 + l15;
      af[m] = *reinterpret_cast<const bf16x8*>(&As[row*32 + ((u ^ ((row>>1)&3)) * 8)]);
    }
#pragma unroll
    for (int n = 0; n < 4; n++){
      int row = wc*64 + n*16 + l15;
      bfr[n] = *reinterpret_cast<const bf16x8*>(&Bs[row*32 + ((u ^ ((row>>1)&3)) * 8)]);
    }
#pragma unroll
    for (int m = 0; m < 4; m++)
#pragma unroll
      for (int n = 0; n < 4; n++)
        acc[m][n] = __builtin_amdgcn_mfma_f32_16x16x32_bf16(af[m], bfr[n], acc[m][n], 0, 0, 0);
  }

  // epilogue: C/D layout col=lane&15, row=(lane>>4)*4+j
#pragma unroll
  for (int m = 0; m < 4; m++)
#pragma unroll
    for (int n = 0; n < 4; n++)
#pragma unroll
      for (int j = 0; j < 4; j++){
        int row = bm + wr*64 + m*16 + u*4 + j;
        int col = bn + wc*64 + n*16 + l15;
        C[(size_t)row * N + col] = acc[m][n][j];
      }
}

// ---------------- fused RMSNorm + RoPE + bf16 cast (q, k only) ----------------
// qkv: [SEQ][3072] f32.  Outputs: qb [SEQ][2048], kb [SEQ][512] bf16.
__global__ __launch_bounds__(256) void k_normrope(const float* __restrict__ qkv,
                                                  const float* __restrict__ cosp,
                                                  const float* __restrict__ sinp,
                                                  const float* __restrict__ qg,
                                                  const float* __restrict__ kg,
                                                  ushort* __restrict__ qb,
                                                  ushort* __restrict__ kb){
  const int s = blockIdx.x;
  const int tid = threadIdx.x, lane = tid & 63, wid = tid >> 6;
  const float* row = qkv + (size_t)s * NQKV;
  const float cs = cosp[s*HDIM + lane];
  const float sn = sinp[s*HDIM + lane];

  for (int hidx = wid; hidx < 40; hidx += 4){
    const bool isq = hidx < 32;
    const int col = isq ? hidx*64 : 2048 + (hidx-32)*64;
    float x = row[col + lane];
    float ss = x * x;
#pragma unroll
    for (int m = 1; m < 64; m <<= 1) ss += __shfl_xor(ss, m);
    float r = rsqrtf(ss * (1.0f/64.0f) + 1e-6f);
    float y = x * r * (isq ? qg : kg)[lane];
    // HF RoPE: out[d] = y[d]*cos[d] + (d<32 ? -y[d+32] : y[d-32])*sin[d]
    float p = __shfl_xor(y, 32);
    float out = y * cs + (lane < 32 ? -p : p) * sn;
    ushort o = f2bf(out);
    if (isq) qb[(size_t)s*2048 + hidx*64 + lane] = o;
    else     kb[(size_t)s*512 + (hidx-32)*64 + lane] = o;
  }
}

// ---------------- V transpose: qkvf v-section (f32) -> vtb bf16 [g][d][s] ----
__global__ __launch_bounds__(256) void k_vtrans(const float* __restrict__ qkvf,
                                                ushort* __restrict__ vtb){
  __shared__ ushort tile[64][68];     // [d][s], pad 68 (136B rows, 8B-aligned)
  const int g = blockIdx.x >> 5, st = blockIdx.x & 31;
  const int tid = threadIdx.x;
#pragma unroll
  for (int i = 0; i < 4; i++){
    int idx = i*256 + tid;
    int r = idx >> 4, c4 = idx & 15;       // r: s-row 0..63, c4: 4-d group
    float4 v = *reinterpret_cast<const float4*>(
        qkvf + (size_t)(st*64 + r)*NQKV + 2560 + g*64 + c4*4);
    tile[c4*4+0][r] = f2bf(v.x);
    tile[c4*4+1][r] = f2bf(v.y);
    tile[c4*4+2][r] = f2bf(v.z);
    tile[c4*4+3][r] = f2bf(v.w);
  }
  __syncthreads();
#pragma unroll
  for (int i = 0; i < 4; i++){
    int idx = i*256 + tid;
    int d = idx >> 4, s4 = idx & 15;
    ushort4 o = *reinterpret_cast<const ushort4*>(&tile[d][s4*4]);
    *reinterpret_cast<ushort4*>(vtb + (size_t)(g*64 + d)*SEQ + st*64 + s4*4) = o;
  }
}

// ---------------- causal flash GQA attention ----------------
// grid: 512 blocks = 16 q-blocks (descending) x 32 heads. 256 thr = 4 waves.
// q-tile 128 rows/block; each wave owns 32 rows (two 16-row fragments).
// K,V^T double-buffered in LDS; one barrier per KV tile.
__global__ __launch_bounds__(256) void k_attn(const ushort* __restrict__ qbuf,
                                              const ushort* __restrict__ kbuf,
                                              const ushort* __restrict__ vtb,
                                              ushort* __restrict__ ctx){
  __shared__ ushort Kd[2][64*64];       // swizzled K tiles   (16 KB)
  __shared__ ushort Vd[2][64*64];       // swizzled V^T tiles (16 KB)
  __shared__ ushort Plds[4][32*72];     // per-wave P         (18 KB)

  const int bx = blockIdx.x;
  const int h  = bx & 31;
  const int qblk = 15 - (bx >> 5);      // descending: longest blocks first
  const int g = h >> 2;
  const int tid = threadIdx.x, lane = tid & 63, wid = tid >> 6;
  const int l15 = lane & 15, u = lane >> 4;
  const int q0 = qblk*128 + wid*32;     // wave's first q-row
  const int tmax = 2*qblk + 1;          // last KV tile (inclusive)

  // Q fragments in registers (A-layout: row=lane&15, k=(lane>>4)*8 within chunk)
  bf16x8 qf[2][2];
#pragma unroll
  for (int m = 0; m < 2; m++)
#pragma unroll
    for (int kc = 0; kc < 2; kc++)
      qf[m][kc] = *reinterpret_cast<const bf16x8*>(
          qbuf + (size_t)(q0 + m*16 + l15)*2048 + h*64 + kc*32 + u*8);

  f32x4 o[2][4] = {};
  float mrun[2][4], lrun[2][4];
#pragma unroll
  for (int m = 0; m < 2; m++)
#pragma unroll
    for (int j = 0; j < 4; j++){ mrun[m][j] = -1e30f; lrun[m][j] = 0.f; }

  // staging addresses: 8 chunks of 1KB per tile (8 rows x 128B); wave does 2+2
  const int srow = wid*16 + (lane >> 3);          // 0..63 over chunk pairs
  const int scol = ((lane & 7) ^ (srow & 7)) * 8; // pre-swizzled 16B slot (shorts)
  const ushort* ksrc0 = kbuf + (size_t)srow*512 + g*64 + scol;         // + t*64*512
  const ushort* vsrc0 = vtb  + (size_t)(g*64 + srow)*SEQ + scol;       // + t*64

  auto STAGE = [&](int buf, int t){
    const ushort* ks = ksrc0 + (size_t)t*64*512;
    gl_lds16(ks,         &Kd[buf][wid*1024]);
    gl_lds16(ks + 8*512, &Kd[buf][wid*1024 + 512]);
    const ushort* vs = vsrc0 + t*64;
    gl_lds16(vs,          &Vd[buf][wid*1024]);
    gl_lds16(vs + 8*SEQ,  &Vd[buf][wid*1024 + 512]);
  };

  STAGE(0, 0);
  __syncthreads();   // drains vmcnt(0): tile 0 visible

  for (int t = 0; t <= tmax; t++){
    const int cur = t & 1;
    if (t < tmax) STAGE(cur ^ 1, t + 1);

    const ushort* Kb = &Kd[cur][0];
    const ushort* Vb = &Vd[cur][0];
    const bool full = (t*64 + 63) <= q0;   // wave-uniform: no masking needed

    // ---- scores S = QK^T * 0.125 with causal mask ----
    f32x4 sc[2][4];
#pragma unroll
    for (int kb = 0; kb < 4; kb++){
      const int key0 = t*64 + kb*16;
      const int keyl = kb*16 + l15;
      bf16x8 bfr[2];
#pragma unroll
      for (int kc = 0; kc < 2; kc++)
        bfr[kc] = *reinterpret_cast<const bf16x8*>(
            &Kb[keyl*64 + (((kc<<2)|u) ^ (keyl & 7))*8]);
#pragma unroll
      for (int m = 0; m < 2; m++){
        if (key0 <= q0 + m*16 + 15){
          f32x4 a = {};
          a = __builtin_amdgcn_mfma_f32_16x16x32_bf16(qf[m][0], bfr[0], a, 0, 0, 0);
          a = __builtin_amdgcn_mfma_f32_16x16x32_bf16(qf[m][1], bfr[1], a, 0, 0, 0);
          if (full){
#pragma unroll
            for (int j = 0; j < 4; j++) sc[m][kb][j] = a[j] * 0.125f;
          } else {
            const int key = key0 + l15;
#pragma unroll
            for (int j = 0; j < 4; j++){
              int qr = q0 + m*16 + u*4 + j;
              sc[m][kb][j] = (key > qr) ? -1e30f : a[j] * 0.125f;
            }
          }
        } else {
#pragma unroll
          for (int j = 0; j < 4; j++) sc[m][kb][j] = -1e30f;
        }
      }
    }

    // ---- online softmax (rows owned by 16-lane groups) ----
#pragma unroll
    for (int m = 0; m < 2; m++){
      float alpha[4];
#pragma unroll
      for (int j = 0; j < 4; j++){
        float m0 = fmaxf(fmaxf(sc[m][0][j], sc[m][1][j]),
                         fmaxf(sc[m][2][j], sc[m][3][j]));
#pragma unroll
        for (int msk = 1; msk < 16; msk <<= 1) m0 = fmaxf(m0, __shfl_xor(m0, msk));
        float mn = fmaxf(mrun[m][j], m0);
        alpha[j] = __expf(mrun[m][j] - mn);
        mrun[m][j] = mn;
      }
#pragma unroll
      for (int kb = 0; kb < 4; kb++)
#pragma unroll
        for (int j = 0; j < 4; j++)
          sc[m][kb][j] = __expf(sc[m][kb][j] - mrun[m][j]);
#pragma unroll
      for (int j = 0; j < 4; j++){
        float s0 = sc[m][0][j] + sc[m][1][j] + sc[m][2][j] + sc[m][3][j];
#pragma unroll
        for (int msk = 1; msk < 16; msk <<= 1) s0 += __shfl_xor(s0, msk);
        lrun[m][j] = lrun[m][j]*alpha[j] + s0;
      }
#pragma unroll
      for (int d0 = 0; d0 < 4; d0++)
#pragma unroll
        for (int j = 0; j < 4; j++) o[m][d0][j] *= alpha[j];

      // P -> bf16 -> wave-private LDS (D-layout write, A-layout read)
#pragma unroll
      for (int kb = 0; kb < 4; kb++)
#pragma unroll
        for (int j = 0; j < 4; j++)
          Plds[wid][(m*16 + u*4 + j)*72 + kb*16 + l15] = f2bf(sc[m][kb][j]);
    }

    // ---- O += P @ V ----
#pragma unroll
    for (int kc = 0; kc < 2; kc++){
      bf16x8 pa0 = *reinterpret_cast<const bf16x8*>(&Plds[wid][l15*72 + kc*32 + u*8]);
      bf16x8 pa1 = *reinterpret_cast<const bf16x8*>(&Plds[wid][(16 + l15)*72 + kc*32 + u*8]);
#pragma unroll
      for (int d0 = 0; d0 < 4; d0++){
        const int vrow = d0*16 + l15;
        bf16x8 vb8 = *reinterpret_cast<const bf16x8*>(
            &Vb[vrow*64 + (((kc<<2)|u) ^ (vrow & 7))*8]);
        o[0][d0] = __builtin_amdgcn_mfma_f32_16x16x32_bf16(pa0, vb8, o[0][d0], 0, 0, 0);
        o[1][d0] = __builtin_amdgcn_mfma_f32_16x16x32_bf16(pa1, vb8, o[1][d0], 0, 0, 0);
      }
    }

    __syncthreads();  // publishes tile t+1 (vmcnt drain) + protects buffer reuse
  }

  // epilogue: normalize and store ctx bf16
#pragma unroll
  for (int m = 0; m < 2; m++)
#pragma unroll
    for (int d0 = 0; d0 < 4; d0++)
#pragma unroll
      for (int j = 0; j < 4; j++){
        float val = o[m][d0][j] / lrun[m][j];
        ctx[(size_t)(q0 + m*16 + u*4 + j)*2048 + h*64 + d0*16 + l15] = f2bf(val);
      }
}

// ---------------- launcher ----------------
extern "C" void kernel_launch(void* const* d_in, const int* in_sizes, int n_in,
                              void* d_out, int out_size, void* d_ws, size_t ws_size,
                              hipStream_t stream){
  const float* x    = (const float*)d_in[0];
  // d_in[1] = mask (unused; causal mask computed analytically)
  const float* cosp = (const float*)d_in[2];
  const float* sinp = (const float*)d_in[3];
  const float* wq   = (const float*)d_in[4];
  const float* wk   = (const float*)d_in[5];
  const float* wv   = (const float*)d_in[6];
  const float* wo   = (const float*)d_in[7];
  const float* qg   = (const float*)d_in[8];
  const float* kg   = (const float*)d_in[9];
  float* out = (float*)d_out;

  char* ws = (char*)d_ws;
  ushort* xb   = (ushort*)(ws);                    //  8 MB  x bf16
  ushort* wcat = (ushort*)(ws + 8388608);          // 12 MB  [wq;wk;wv] bf16 [3072][2048]
  ushort* wob  = (ushort*)(ws + 20971520);         //  8 MB  wo bf16
  float*  qkvf = (float* )(ws + 29360128);         // 24 MB  qkv f32 [2048][3072]
  ushort* qbuf = (ushort*)(ws + 54525952);         //  8 MB  q bf16 [2048][2048]
  ushort* kbuf = (ushort*)(ws + 62914560);         //  2 MB  k bf16 [2048][512]
  ushort* vtb  = (ushort*)(ws + 65011712);         //  2 MB  v^T bf16 [8*64][2048]
  ushort* ctxb = (ushort*)(ws + 67108864);         //  8 MB  ctx bf16 [2048][2048]
  // total 75,497,472 bytes

  k_cvt<<<4096, 256, 0, stream>>>(x,  xb,   1048576);
  k_cvt<<<4096, 256, 0, stream>>>(wq, wcat, 1048576);
  k_cvt<<<1024, 256, 0, stream>>>(wk, wcat + 2048*2048, 262144);
  k_cvt<<<1024, 256, 0, stream>>>(wv, wcat + 2560*2048, 262144);
  k_cvt<<<4096, 256, 0, stream>>>(wo, wob,  1048576);

  k_gemm_bt<<<dim3(24, 16), 256, 0, stream>>>(xb, wcat, qkvf, 2048, 3072, 2048);
  k_normrope<<<2048, 256, 0, stream>>>(qkvf, cosp, sinp, qg, kg, qbuf, kbuf);
  k_vtrans<<<256, 256, 0, stream>>>(qkvf, vtb);
  k_attn<<<512, 256, 0, stream>>>(qbuf, kbuf, vtb, ctxb);
  k_gemm_bt<<<dim3(16, 16), 256, 0, stream>>>(ctxb, wob, out, 2048, 2048, 2048);
}

// Round 3
// 186.568 us; speedup vs baseline: 1.6156x; 1.2682x over previous
//
#include <hip/hip_runtime.h>
#include <stdint.h>

// Problem constants (fixed-shape problem)
#define SEQ    2048
#define DMODEL 2048
#define NHEAD  32
#define NKV    8
#define HDIM   64
#define NQKV   3072   // 2048 q + 512 k + 512 v

typedef __bf16 bf16x8 __attribute__((ext_vector_type(8)));
typedef float  f32x4  __attribute__((ext_vector_type(4)));

#define SCALE2 0.180336880f   // 0.125 * log2(e): scores land in log2 domain
#define THR2   12.0f          // defer-max threshold (log2 domain); P <= 2^12

__device__ __forceinline__ ushort bf(float f){
  __bf16 h = (__bf16)f;               // native RNE convert on gfx950
  return __builtin_bit_cast(unsigned short, h);
}

__device__ __forceinline__ void gl_lds16(const void* g, void* l){
  __builtin_amdgcn_global_load_lds(
      (const __attribute__((address_space(1))) uint32_t*)g,
      (__attribute__((address_space(3))) uint32_t*)l, 16, 0, 0);
}

// ---------------- f32 -> bf16 convert (vector x4) ----------------
__global__ __launch_bounds__(256) void k_cvt(const float* __restrict__ src,
                                             ushort* __restrict__ dst, int n4){
  int i = blockIdx.x * 256 + threadIdx.x;
  if (i >= n4) return;
  float4 v = reinterpret_cast<const float4*>(src)[i];
  ushort4 o;
  o.x = bf(v.x); o.y = bf(v.y); o.z = bf(v.z); o.w = bf(v.w);
  reinterpret_cast<ushort4*>(dst)[i] = o;
}

// ------------- fused wq/wk/wv convert into contiguous wcat -------------
__global__ __launch_bounds__(256) void k_cvtw(const float* __restrict__ wq,
                                              const float* __restrict__ wk,
                                              const float* __restrict__ wv,
                                              ushort* __restrict__ dst){
  int i = blockIdx.x * 256 + threadIdx.x;   // float4 index, 0..1572863
  const float* src; int off;
  if (i < 1048576)      { src = wq; off = 0; }
  else if (i < 1310720) { src = wk; off = 1048576; }
  else                  { src = wv; off = 1310720; }
  float4 v = reinterpret_cast<const float4*>(src)[i - off];
  ushort4 o;
  o.x = bf(v.x); o.y = bf(v.y); o.z = bf(v.z); o.w = bf(v.w);
  reinterpret_cast<ushort4*>(dst)[i] = o;
}

// ---------------- GEMM: C[m][n] = sum_k A[m][k] * B[n][k] ----------------
// 128x128 tile, BK=64 (m97 structure), 4 waves (2x2), global_load_lds into
// linear LDS with XOR-swizzled source + matching swizzled ds_read.
__global__ __launch_bounds__(256) void k_gemm_bt(const ushort* __restrict__ A,
                                                 const ushort* __restrict__ B,
                                                 float* __restrict__ C,
                                                 int M, int N, int K){
  __shared__ ushort As[128*64];
  __shared__ ushort Bs[128*64];
  const int tid  = threadIdx.x;
  const int lane = tid & 63;
  const int wid  = tid >> 6;
  const int bm = blockIdx.y * 128;
  const int bn = blockIdx.x * 128;
  const int wr = wid >> 1, wc = wid & 1;
  const int l15 = lane & 15, u = lane >> 4;

  // staging: wave covers 32 rows (4 chunks of 8 rows x 128B)
  const int srow = wid*32 + (lane >> 3);
  const int scol = ((lane & 7) ^ (lane >> 3)) * 8;   // pre-swizzled k-chunk
  const ushort* Abase = A + (size_t)(bm + srow) * K + scol;
  const ushort* Bbase = B + (size_t)(bn + srow) * K + scol;

  f32x4 acc[4][4] = {};

  for (int k0 = 0; k0 < K; k0 += 64){
    __syncthreads();
#pragma unroll
    for (int c = 0; c < 4; c++){
      gl_lds16(Abase + k0 + (size_t)c*8*K, As + (wid*32 + c*8)*64);
      gl_lds16(Bbase + k0 + (size_t)c*8*K, Bs + (wid*32 + c*8)*64);
    }
    __syncthreads();   // drains vmcnt(0): staged data visible

#pragma unroll
    for (int kc = 0; kc < 2; kc++){
      bf16x8 af[4], bfr[4];
#pragma unroll
      for (int m = 0; m < 4; m++){
        int row = wr*64 + m*16 + l15;
        af[m] = *reinterpret_cast<const bf16x8*>(&As[row*64 + (((kc*4+u) ^ (row&7))*8)]);
      }
#pragma unroll
      for (int n = 0; n < 4; n++){
        int row = wc*64 + n*16 + l15;
        bfr[n] = *reinterpret_cast<const bf16x8*>(&Bs[row*64 + (((kc*4+u) ^ (row&7))*8)]);
      }
#pragma unroll
      for (int m = 0; m < 4; m++)
#pragma unroll
        for (int n = 0; n < 4; n++)
          acc[m][n] = __builtin_amdgcn_mfma_f32_16x16x32_bf16(af[m], bfr[n], acc[m][n], 0, 0, 0);
    }
  }

  // epilogue: C/D layout col=lane&15, row=(lane>>4)*4+j
#pragma unroll
  for (int m = 0; m < 4; m++)
#pragma unroll
    for (int n = 0; n < 4; n++)
#pragma unroll
      for (int j = 0; j < 4; j++){
        int row = bm + wr*64 + m*16 + u*4 + j;
        int col = bn + wc*64 + n*16 + l15;
        C[(size_t)row * N + col] = acc[m][n][j];
      }
}

// ---------------- fused RMSNorm + RoPE + bf16 cast (q, k only) ----------------
// qkv: [SEQ][3072] f32.  Outputs: qb [SEQ][2048] (pre-scaled by SCALE2),
// kb [SEQ][512] bf16.
__global__ __launch_bounds__(256) void k_normrope(const float* __restrict__ qkv,
                                                  const float* __restrict__ cosp,
                                                  const float* __restrict__ sinp,
                                                  const float* __restrict__ qg,
                                                  const float* __restrict__ kg,
                                                  ushort* __restrict__ qb,
                                                  ushort* __restrict__ kb){
  const int s = blockIdx.x;
  const int tid = threadIdx.x, lane = tid & 63, wid = tid >> 6;
  const float* row = qkv + (size_t)s * NQKV;
  const float cs = cosp[s*HDIM + lane];
  const float sn = sinp[s*HDIM + lane];

  for (int hidx = wid; hidx < 40; hidx += 4){
    const bool isq = hidx < 32;
    const int col = isq ? hidx*64 : 2048 + (hidx-32)*64;
    float x = row[col + lane];
    float ss = x * x;
#pragma unroll
    for (int m = 1; m < 64; m <<= 1) ss += __shfl_xor(ss, m);
    float r = rsqrtf(ss * (1.0f/64.0f) + 1e-6f);
    float y = x * r * (isq ? qg : kg)[lane];
    // HF RoPE: out[d] = y[d]*cos[d] + (d<32 ? -y[d+32] : y[d-32])*sin[d]
    float p = __shfl_xor(y, 32);
    float out = y * cs + (lane < 32 ? -p : p) * sn;
    if (isq) qb[(size_t)s*2048 + hidx*64 + lane] = bf(out * SCALE2);
    else     kb[(size_t)s*512 + (hidx-32)*64 + lane] = bf(out);
  }
}

// ---------------- V transpose: qkvf v-section (f32) -> vtb bf16 [g][d][s] ----
__global__ __launch_bounds__(256) void k_vtrans(const float* __restrict__ qkvf,
                                                ushort* __restrict__ vtb){
  __shared__ ushort tile[64][68];     // [d][s], pad 68 (136B rows, 8B-aligned)
  const int g = blockIdx.x >> 5, st = blockIdx.x & 31;
  const int tid = threadIdx.x;
#pragma unroll
  for (int i = 0; i < 4; i++){
    int idx = i*256 + tid;
    int r = idx >> 4, c4 = idx & 15;       // r: s-row 0..63, c4: 4-d group
    float4 v = *reinterpret_cast<const float4*>(
        qkvf + (size_t)(st*64 + r)*NQKV + 2560 + g*64 + c4*4);
    tile[c4*4+0][r] = bf(v.x);
    tile[c4*4+1][r] = bf(v.y);
    tile[c4*4+2][r] = bf(v.z);
    tile[c4*4+3][r] = bf(v.w);
  }
  __syncthreads();
#pragma unroll
  for (int i = 0; i < 4; i++){
    int idx = i*256 + tid;
    int d = idx >> 4, s4 = idx & 15;
    ushort4 o = *reinterpret_cast<const ushort4*>(&tile[d][s4*4]);
    *reinterpret_cast<ushort4*>(vtb + (size_t)(g*64 + d)*SEQ + st*64 + s4*4) = o;
  }
}

// ---------------- causal flash GQA attention (swapped QK^T) ----------------
// grid: 512 blocks; balanced mapping: bx<256 -> qblk=15-(bx>>5) (desc),
// bx>=256 -> qblk=(bx-256)>>5 (asc) so co-resident pairs sum to 34 tiles.
// 256 thr = 4 waves, 32 q-rows/wave. S^T = mfma(K,Q): q-row in-lane softmax.
__global__ __launch_bounds__(256) void k_attn(const ushort* __restrict__ qbuf,
                                              const ushort* __restrict__ kbuf,
                                              const ushort* __restrict__ vtb,
                                              ushort* __restrict__ ctx){
  __shared__ ushort Kd[2][64*64];       // swizzled K tiles   (16 KB)
  __shared__ ushort Vd[2][64*64];       // swizzled V^T tiles (16 KB)
  __shared__ ushort Plds[4][32*72];     // per-wave P [row][key] (18 KB)

  const int bx = blockIdx.x;
  const int h  = bx & 31;
  const int qblk = (bx < 256) ? (15 - (bx >> 5)) : ((bx - 256) >> 5);
  const int g = h >> 2;
  const int tid = threadIdx.x, lane = tid & 63, wid = tid >> 6;
  const int l15 = lane & 15, u = lane >> 4;
  const int q0 = qblk*128 + wid*32;     // wave's first q-row
  const int tmax = 2*qblk + 1;          // last KV tile (inclusive)
  ushort* Pw = &Plds[wid][0];

  // Q fragments (B-operand: col=l15 -> q-row, k=(lane>>4)*8 within 32-chunk)
  bf16x8 qf[2][2];
#pragma unroll
  for (int m = 0; m < 2; m++)
#pragma unroll
    for (int kc = 0; kc < 2; kc++)
      qf[m][kc] = *reinterpret_cast<const bf16x8*>(
          qbuf + (size_t)(q0 + m*16 + l15)*2048 + h*64 + kc*32 + u*8);

  f32x4 o[2][4] = {};
  float mrun[2] = {-1e30f, -1e30f};     // per-lane: stats of q-row l15 (frag m)
  float lrun[2] = {0.f, 0.f};
  int u4j[4];                            // shfl src lane for O-row u*4+j
#pragma unroll
  for (int j = 0; j < 4; j++) u4j[j] = u*4 + j;

  // staging: 8 chunks of 1KB per tile (8 rows x 128B); wave does 2 K + 2 V
  const int srow = wid*16 + (lane >> 3);
  const int scol = ((lane & 7) ^ (lane >> 3)) * 8;
  const ushort* ksrc0 = kbuf + (size_t)srow*512 + g*64 + scol;       // + t*64*512
  const ushort* vsrc0 = vtb  + (size_t)(g*64 + srow)*SEQ + scol;     // + t*64

  auto STAGE = [&](int buf, int t){
    const ushort* ks = ksrc0 + (size_t)t*64*512;
    gl_lds16(ks,         &Kd[buf][wid*1024]);
    gl_lds16(ks + 8*512, &Kd[buf][wid*1024 + 512]);
    const ushort* vs = vsrc0 + t*64;
    gl_lds16(vs,          &Vd[buf][wid*1024]);
    gl_lds16(vs + 8*SEQ,  &Vd[buf][wid*1024 + 512]);
  };

  STAGE(0, 0);
  __syncthreads();   // drains vmcnt(0): tile 0 visible

  for (int t = 0; t <= tmax; t++){
    const int cur = t & 1;
    if (t < tmax) STAGE(cur ^ 1, t + 1);

    const ushort* Kb = &Kd[cur][0];
    const ushort* Vb = &Vd[cur][0];
    const bool full = (t*64 + 63) <= q0;   // wave-uniform

    // ---- S^T = mfma(K, Q): lane holds key=kb*16+u*4+j for q-row l15 ----
    f32x4 st[2][4];
#pragma unroll
    for (int kb = 0; kb < 4; kb++){
      const int key0 = t*64 + kb*16;
      const int keyl = kb*16 + l15;
      bf16x8 kf0 = *reinterpret_cast<const bf16x8*>(&Kb[keyl*64 + ((u     ^ (keyl&7))*8)]);
      bf16x8 kf1 = *reinterpret_cast<const bf16x8*>(&Kb[keyl*64 + (((4|u) ^ (keyl&7))*8)]);
#pragma unroll
      for (int m = 0; m < 2; m++){
        if (key0 <= q0 + m*16 + 15){
          f32x4 a = {};
          a = __builtin_amdgcn_mfma_f32_16x16x32_bf16(kf0, qf[m][0], a, 0, 0, 0);
          a = __builtin_amdgcn_mfma_f32_16x16x32_bf16(kf1, qf[m][1], a, 0, 0, 0);
          st[m][kb] = a;
        } else {
          st[m][kb] = (f32x4){-1e30f, -1e30f, -1e30f, -1e30f};
        }
      }
    }
    if (!full){
      const int keyb = t*64 + u*4;
#pragma unroll
      for (int m = 0; m < 2; m++){
        const int qr = q0 + m*16 + l15;
#pragma unroll
        for (int kb = 0; kb < 4; kb++)
#pragma unroll
          for (int j = 0; j < 4; j++)
            st[m][kb][j] = (keyb + kb*16 + j > qr) ? -1e30f : st[m][kb][j];
      }
    }

    // ---- online softmax, in-lane rows (defer-max, log2 domain) ----
#pragma unroll
    for (int m = 0; m < 2; m++){
      // row max: 15 in-lane + 2-shfl butterfly over u
      f32x4 mx = st[m][0];
#pragma unroll
      for (int kb = 1; kb < 4; kb++)
#pragma unroll
        for (int j = 0; j < 4; j++) mx[j] = fmaxf(mx[j], st[m][kb][j]);
      float tm = fmaxf(fmaxf(mx[0], mx[1]), fmaxf(mx[2], mx[3]));
      tm = fmaxf(tm, __shfl_xor(tm, 16));
      tm = fmaxf(tm, __shfl_xor(tm, 32));

      if (__any(tm > mrun[m] + THR2)){
        float mn = fmaxf(mrun[m], tm);
        float al = exp2f(mrun[m] - mn);
        mrun[m] = mn;
        lrun[m] *= al;
        float alo[4];
#pragma unroll
        for (int j = 0; j < 4; j++) alo[j] = __shfl(al, u4j[j]);
#pragma unroll
        for (int d0 = 0; d0 < 4; d0++)
#pragma unroll
          for (int j = 0; j < 4; j++) o[m][d0][j] *= alo[j];
      }

      // exp + in-lane row sum + packed P write
      float ls = 0.f;
#pragma unroll
      for (int kb = 0; kb < 4; kb++){
        ushort4 w;
#pragma unroll
        for (int j = 0; j < 4; j++){
          float p = exp2f(st[m][kb][j] - mrun[m]);
          st[m][kb][j] = p;
          ls += p;
        }
        w.x = bf(st[m][kb][0]); w.y = bf(st[m][kb][1]);
        w.z = bf(st[m][kb][2]); w.w = bf(st[m][kb][3]);
        *reinterpret_cast<ushort4*>(&Pw[(m*16 + l15)*72 + kb*16 + u*4]) = w;
      }
      ls += __shfl_xor(ls, 16);
      ls += __shfl_xor(ls, 32);
      lrun[m] += ls;
    }

    // ---- O += P @ V  (A rows = q-rows from Plds, B cols = d from Vt) ----
#pragma unroll
    for (int kc = 0; kc < 2; kc++){
      bf16x8 pa0 = *reinterpret_cast<const bf16x8*>(&Pw[l15*72 + kc*32 + u*8]);
      bf16x8 pa1 = *reinterpret_cast<const bf16x8*>(&Pw[(16 + l15)*72 + kc*32 + u*8]);
#pragma unroll
      for (int d0 = 0; d0 < 4; d0++){
        const int vrow = d0*16 + l15;
        bf16x8 vb8 = *reinterpret_cast<const bf16x8*>(
            &Vb[vrow*64 + (((kc*4+u) ^ (vrow&7))*8)]);
        o[0][d0] = __builtin_amdgcn_mfma_f32_16x16x32_bf16(pa0, vb8, o[0][d0], 0, 0, 0);
        o[1][d0] = __builtin_amdgcn_mfma_f32_16x16x32_bf16(pa1, vb8, o[1][d0], 0, 0, 0);
      }
    }

    __syncthreads();  // publishes tile t+1 (vmcnt drain) + protects buffer reuse
  }

  // epilogue: redistribute 1/lrun (l15-domain) to O-rows (u*4+j) and store
#pragma unroll
  for (int m = 0; m < 2; m++){
    float inv = 1.0f / lrun[m];
    float invo[4];
#pragma unroll
    for (int j = 0; j < 4; j++) invo[j] = __shfl(inv, u4j[j]);
#pragma unroll
    for (int d0 = 0; d0 < 4; d0++)
#pragma unroll
      for (int j = 0; j < 4; j++){
        float val = o[m][d0][j] * invo[j];
        ctx[(size_t)(q0 + m*16 + u*4 + j)*2048 + h*64 + d0*16 + l15] = bf(val);
      }
  }
}

// ---------------- launcher ----------------
extern "C" void kernel_launch(void* const* d_in, const int* in_sizes, int n_in,
                              void* d_out, int out_size, void* d_ws, size_t ws_size,
                              hipStream_t stream){
  const float* x    = (const float*)d_in[0];
  // d_in[1] = mask (unused; causal mask computed analytically)
  const float* cosp = (const float*)d_in[2];
  const float* sinp = (const float*)d_in[3];
  const float* wq   = (const float*)d_in[4];
  const float* wk   = (const float*)d_in[5];
  const float* wv   = (const float*)d_in[6];
  const float* wo   = (const float*)d_in[7];
  const float* qg   = (const float*)d_in[8];
  const float* kg   = (const float*)d_in[9];
  float* out = (float*)d_out;

  char* ws = (char*)d_ws;
  ushort* xb   = (ushort*)(ws);                    //  8 MB  x bf16
  ushort* wcat = (ushort*)(ws + 8388608);          // 12 MB  [wq;wk;wv] bf16 [3072][2048]
  ushort* wob  = (ushort*)(ws + 20971520);         //  8 MB  wo bf16
  float*  qkvf = (float* )(ws + 29360128);         // 24 MB  qkv f32 [2048][3072]
  ushort* qbuf = (ushort*)(ws + 54525952);         //  8 MB  q bf16 [2048][2048] (pre-scaled)
  ushort* kbuf = (ushort*)(ws + 62914560);         //  2 MB  k bf16 [2048][512]
  ushort* vtb  = (ushort*)(ws + 65011712);         //  2 MB  v^T bf16 [8*64][2048]
  ushort* ctxb = (ushort*)(ws + 67108864);         //  8 MB  ctx bf16 [2048][2048]
  // total 75,497,472 bytes

  k_cvt<<<4096, 256, 0, stream>>>(x,  xb,  1048576);
  k_cvt<<<4096, 256, 0, stream>>>(wo, wob, 1048576);
  k_cvtw<<<6144, 256, 0, stream>>>(wq, wk, wv, wcat);

  k_gemm_bt<<<dim3(24, 16), 256, 0, stream>>>(xb, wcat, qkvf, 2048, 3072, 2048);
  k_normrope<<<2048, 256, 0, stream>>>(qkvf, cosp, sinp, qg, kg, qbuf, kbuf);
  k_vtrans<<<256, 256, 0, stream>>>(qkvf, vtb);
  k_attn<<<512, 256, 0, stream>>>(qbuf, kbuf, vtb, ctxb);
  k_gemm_bt<<<dim3(16, 16), 256, 0, stream>>>(ctxb, wob, out, 2048, 2048, 2048);
}

// Round 4
// 168.743 us; speedup vs baseline: 1.7863x; 1.1056x over previous
//
#include <hip/hip_runtime.h>
#include <stdint.h>

// Problem constants (fixed-shape problem)
#define SEQ    2048
#define DMODEL 2048
#define NHEAD  32
#define NKV    8
#define HDIM   64
#define NQKV   3072   // 2048 q + 512 k + 512 v

typedef __bf16 bf16x8 __attribute__((ext_vector_type(8)));
typedef float  f32x4  __attribute__((ext_vector_type(4)));

#define SCALE2 0.180336880f   // 0.125 * log2(e): scores land in log2 domain
#define THR2   12.0f          // defer-max threshold (log2 domain); P <= 2^12

__device__ __forceinline__ ushort bf(float f){
  __bf16 h = (__bf16)f;               // native RNE convert on gfx950
  return __builtin_bit_cast(unsigned short, h);
}

__device__ __forceinline__ void gl_lds16(const void* g, void* l){
  __builtin_amdgcn_global_load_lds(
      (const __attribute__((address_space(1))) uint32_t*)g,
      (__attribute__((address_space(3))) uint32_t*)l, 16, 0, 0);
}

// ---------------- f32 -> bf16 convert (vector x4) ----------------
__global__ __launch_bounds__(256) void k_cvt(const float* __restrict__ src,
                                             ushort* __restrict__ dst, int n4){
  int i = blockIdx.x * 256 + threadIdx.x;
  if (i >= n4) return;
  float4 v = reinterpret_cast<const float4*>(src)[i];
  ushort4 o;
  o.x = bf(v.x); o.y = bf(v.y); o.z = bf(v.z); o.w = bf(v.w);
  reinterpret_cast<ushort4*>(dst)[i] = o;
}

// ------------- fused wq/wk/wv convert into contiguous wcat -------------
__global__ __launch_bounds__(256) void k_cvtw(const float* __restrict__ wq,
                                              const float* __restrict__ wk,
                                              const float* __restrict__ wv,
                                              ushort* __restrict__ dst){
  int i = blockIdx.x * 256 + threadIdx.x;   // float4 index, 0..1572863
  const float* src; int off;
  if (i < 1048576)      { src = wq; off = 0; }
  else if (i < 1310720) { src = wk; off = 1048576; }
  else                  { src = wv; off = 1310720; }
  float4 v = reinterpret_cast<const float4*>(src)[i - off];
  ushort4 o;
  o.x = bf(v.x); o.y = bf(v.y); o.z = bf(v.z); o.w = bf(v.w);
  reinterpret_cast<ushort4*>(dst)[i] = o;
}

// ---------------- GEMM: C[m][n] = sum_k A[m][k] * B[n][k] ----------------
// 128x128 tile, BK=64 (m97 structure), 4 waves (2x2), global_load_lds into
// linear LDS with XOR-swizzled source + matching swizzled ds_read.
__global__ __launch_bounds__(256) void k_gemm_bt(const ushort* __restrict__ A,
                                                 const ushort* __restrict__ B,
                                                 float* __restrict__ C,
                                                 int M, int N, int K){
  __shared__ ushort As[128*64];
  __shared__ ushort Bs[128*64];
  const int tid  = threadIdx.x;
  const int lane = tid & 63;
  const int wid  = tid >> 6;
  const int bm = blockIdx.y * 128;
  const int bn = blockIdx.x * 128;
  const int wr = wid >> 1, wc = wid & 1;
  const int l15 = lane & 15, u = lane >> 4;

  // staging: wave covers 32 rows (4 chunks of 8 rows x 128B)
  const int srow = wid*32 + (lane >> 3);
  const int scol = ((lane & 7) ^ (lane >> 3)) * 8;   // pre-swizzled k-chunk
  const ushort* Abase = A + (size_t)(bm + srow) * K + scol;
  const ushort* Bbase = B + (size_t)(bn + srow) * K + scol;

  f32x4 acc[4][4] = {};

  for (int k0 = 0; k0 < K; k0 += 64){
    __syncthreads();
#pragma unroll
    for (int c = 0; c < 4; c++){
      gl_lds16(Abase + k0 + (size_t)c*8*K, As + (wid*32 + c*8)*64);
      gl_lds16(Bbase + k0 + (size_t)c*8*K, Bs + (wid*32 + c*8)*64);
    }
    __syncthreads();   // drains vmcnt(0): staged data visible

#pragma unroll
    for (int kc = 0; kc < 2; kc++){
      bf16x8 af[4], bfr[4];
#pragma unroll
      for (int m = 0; m < 4; m++){
        int row = wr*64 + m*16 + l15;
        af[m] = *reinterpret_cast<const bf16x8*>(&As[row*64 + (((kc*4+u) ^ (row&7))*8)]);
      }
#pragma unroll
      for (int n = 0; n < 4; n++){
        int row = wc*64 + n*16 + l15;
        bfr[n] = *reinterpret_cast<const bf16x8*>(&Bs[row*64 + (((kc*4+u) ^ (row&7))*8)]);
      }
#pragma unroll
      for (int m = 0; m < 4; m++)
#pragma unroll
        for (int n = 0; n < 4; n++)
          acc[m][n] = __builtin_amdgcn_mfma_f32_16x16x32_bf16(af[m], bfr[n], acc[m][n], 0, 0, 0);
    }
  }

  // epilogue: C/D layout col=lane&15, row=(lane>>4)*4+j
#pragma unroll
  for (int m = 0; m < 4; m++)
#pragma unroll
    for (int n = 0; n < 4; n++)
#pragma unroll
      for (int j = 0; j < 4; j++){
        int row = bm + wr*64 + m*16 + u*4 + j;
        int col = bn + wc*64 + n*16 + l15;
        C[(size_t)row * N + col] = acc[m][n][j];
      }
}

// ---------------- fused RMSNorm + RoPE + bf16 cast (q, k only) ----------------
// qkv: [SEQ][3072] f32.  Outputs: qb [SEQ][2048] (pre-scaled by SCALE2),
// kb [SEQ][512] bf16.
__global__ __launch_bounds__(256) void k_normrope(const float* __restrict__ qkv,
                                                  const float* __restrict__ cosp,
                                                  const float* __restrict__ sinp,
                                                  const float* __restrict__ qg,
                                                  const float* __restrict__ kg,
                                                  ushort* __restrict__ qb,
                                                  ushort* __restrict__ kb){
  const int s = blockIdx.x;
  const int tid = threadIdx.x, lane = tid & 63, wid = tid >> 6;
  const float* row = qkv + (size_t)s * NQKV;
  const float cs = cosp[s*HDIM + lane];
  const float sn = sinp[s*HDIM + lane];

  for (int hidx = wid; hidx < 40; hidx += 4){
    const bool isq = hidx < 32;
    const int col = isq ? hidx*64 : 2048 + (hidx-32)*64;
    float x = row[col + lane];
    float ss = x * x;
#pragma unroll
    for (int m = 1; m < 64; m <<= 1) ss += __shfl_xor(ss, m);
    float r = rsqrtf(ss * (1.0f/64.0f) + 1e-6f);
    float y = x * r * (isq ? qg : kg)[lane];
    // HF RoPE: out[d] = y[d]*cos[d] + (d<32 ? -y[d+32] : y[d-32])*sin[d]
    float p = __shfl_xor(y, 32);
    float out = y * cs + (lane < 32 ? -p : p) * sn;
    if (isq) qb[(size_t)s*2048 + hidx*64 + lane] = bf(out * SCALE2);
    else     kb[(size_t)s*512 + (hidx-32)*64 + lane] = bf(out);
  }
}

// ---------------- V transpose: qkvf v-section (f32) -> vtb bf16 [g][d][s] ----
__global__ __launch_bounds__(256) void k_vtrans(const float* __restrict__ qkvf,
                                                ushort* __restrict__ vtb){
  __shared__ ushort tile[64][68];     // [d][s], pad 68 (136B rows, 8B-aligned)
  const int g = blockIdx.x >> 5, st = blockIdx.x & 31;
  const int tid = threadIdx.x;
#pragma unroll
  for (int i = 0; i < 4; i++){
    int idx = i*256 + tid;
    int r = idx >> 4, c4 = idx & 15;       // r: s-row 0..63, c4: 4-d group
    float4 v = *reinterpret_cast<const float4*>(
        qkvf + (size_t)(st*64 + r)*NQKV + 2560 + g*64 + c4*4);
    tile[c4*4+0][r] = bf(v.x);
    tile[c4*4+1][r] = bf(v.y);
    tile[c4*4+2][r] = bf(v.z);
    tile[c4*4+3][r] = bf(v.w);
  }
  __syncthreads();
#pragma unroll
  for (int i = 0; i < 4; i++){
    int idx = i*256 + tid;
    int d = idx >> 4, s4 = idx & 15;
    ushort4 o = *reinterpret_cast<const ushort4*>(&tile[d][s4*4]);
    *reinterpret_cast<ushort4*>(vtb + (size_t)(g*64 + d)*SEQ + st*64 + s4*4) = o;
  }
}

// ---------------- causal flash GQA attention (swapped QK^T) ----------------
// grid: 1024 blocks = 32 heads x 32 q-tiles of 64 rows, qt DESCENDING
// (greedy-LPT: long blocks dispatch first, short blocks backfill).
// 256 thr = 4 waves, 16 q-rows/wave. S^T = mfma(K,Q): q-row in-lane softmax.
__global__ __launch_bounds__(256) void k_attn(const ushort* __restrict__ qbuf,
                                              const ushort* __restrict__ kbuf,
                                              const ushort* __restrict__ vtb,
                                              ushort* __restrict__ ctx){
  __shared__ ushort Kd[2][64*64];       // swizzled K tiles   (16 KB)
  __shared__ ushort Vd[2][64*64];       // swizzled V^T tiles (16 KB)
  __shared__ ushort Plds[4][16*72];     // per-wave P [row][key] (9 KB)

  const int bx = blockIdx.x;
  const int h  = bx & 31;
  const int qt = 31 - (bx >> 5);        // descending: longest blocks first
  const int g = h >> 2;
  const int tid = threadIdx.x, lane = tid & 63, wid = tid >> 6;
  const int l15 = lane & 15, u = lane >> 4;
  const int q0 = qt*64 + wid*16;        // wave's first q-row
  const int tmax = qt;                  // last KV tile (inclusive)
  ushort* Pw = &Plds[wid][0];

  // Q fragments (B-operand: col=l15 -> q-row, k=(lane>>4)*8 within 32-chunk)
  bf16x8 qf[2];
#pragma unroll
  for (int kc = 0; kc < 2; kc++)
    qf[kc] = *reinterpret_cast<const bf16x8*>(
        qbuf + (size_t)(q0 + l15)*2048 + h*64 + kc*32 + u*8);

  f32x4 o[4] = {};
  float mrun = -1e30f;                  // per-lane: stats of q-row l15
  float lrun = 0.f;
  int u4j[4];                            // shfl src lane for O-row u*4+j
#pragma unroll
  for (int j = 0; j < 4; j++) u4j[j] = u*4 + j;

  // staging: 8 chunks of 1KB per tile (8 rows x 128B); wave does 2 K + 2 V
  const int srow = wid*16 + (lane >> 3);
  const int scol = ((lane & 7) ^ (lane >> 3)) * 8;
  const ushort* ksrc0 = kbuf + (size_t)srow*512 + g*64 + scol;       // + t*64*512
  const ushort* vsrc0 = vtb  + (size_t)(g*64 + srow)*SEQ + scol;     // + t*64

  auto STAGE = [&](int buf, int t){
    const ushort* ks = ksrc0 + (size_t)t*64*512;
    gl_lds16(ks,         &Kd[buf][wid*1024]);
    gl_lds16(ks + 8*512, &Kd[buf][wid*1024 + 512]);
    const ushort* vs = vsrc0 + t*64;
    gl_lds16(vs,          &Vd[buf][wid*1024]);
    gl_lds16(vs + 8*SEQ,  &Vd[buf][wid*1024 + 512]);
  };

  STAGE(0, 0);
  __syncthreads();   // drains vmcnt(0): tile 0 visible

  for (int t = 0; t <= tmax; t++){
    const int cur = t & 1;
    if (t < tmax) STAGE(cur ^ 1, t + 1);

    const ushort* Kb = &Kd[cur][0];
    const ushort* Vb = &Vd[cur][0];
    const bool full = (t*64 + 63) <= q0;   // wave-uniform

    // ---- S^T = mfma(K, Q): lane holds key=kb*16+u*4+j for q-row l15 ----
    f32x4 st[4];
#pragma unroll
    for (int kb = 0; kb < 4; kb++){
      const int key0 = t*64 + kb*16;
      const int keyl = kb*16 + l15;
      if (key0 <= q0 + 15){
        bf16x8 kf0 = *reinterpret_cast<const bf16x8*>(&Kb[keyl*64 + ((u     ^ (keyl&7))*8)]);
        bf16x8 kf1 = *reinterpret_cast<const bf16x8*>(&Kb[keyl*64 + (((4|u) ^ (keyl&7))*8)]);
        f32x4 a = {};
        a = __builtin_amdgcn_mfma_f32_16x16x32_bf16(kf0, qf[0], a, 0, 0, 0);
        a = __builtin_amdgcn_mfma_f32_16x16x32_bf16(kf1, qf[1], a, 0, 0, 0);
        st[kb] = a;
      } else {
        st[kb] = (f32x4){-1e30f, -1e30f, -1e30f, -1e30f};
      }
    }
    if (!full){
      const int keyb = t*64 + u*4;
      const int qr = q0 + l15;
#pragma unroll
      for (int kb = 0; kb < 4; kb++)
#pragma unroll
        for (int j = 0; j < 4; j++)
          st[kb][j] = (keyb + kb*16 + j > qr) ? -1e30f : st[kb][j];
    }

    // ---- online softmax, in-lane rows (defer-max, log2 domain) ----
    {
      // row max: 15 in-lane + 2-shfl butterfly over u
      f32x4 mx = st[0];
#pragma unroll
      for (int kb = 1; kb < 4; kb++)
#pragma unroll
        for (int j = 0; j < 4; j++) mx[j] = fmaxf(mx[j], st[kb][j]);
      float tm = fmaxf(fmaxf(mx[0], mx[1]), fmaxf(mx[2], mx[3]));
      tm = fmaxf(tm, __shfl_xor(tm, 16));
      tm = fmaxf(tm, __shfl_xor(tm, 32));

      if (__any(tm > mrun + THR2)){
        float mn = fmaxf(mrun, tm);
        float al = exp2f(mrun - mn);
        mrun = mn;
        lrun *= al;
        float alo[4];
#pragma unroll
        for (int j = 0; j < 4; j++) alo[j] = __shfl(al, u4j[j]);
#pragma unroll
        for (int d0 = 0; d0 < 4; d0++)
#pragma unroll
          for (int j = 0; j < 4; j++) o[d0][j] *= alo[j];
      }

      // exp + in-lane row sum + packed P write
      float ls = 0.f;
#pragma unroll
      for (int kb = 0; kb < 4; kb++){
        ushort4 w;
#pragma unroll
        for (int j = 0; j < 4; j++){
          float p = exp2f(st[kb][j] - mrun);
          st[kb][j] = p;
          ls += p;
        }
        w.x = bf(st[kb][0]); w.y = bf(st[kb][1]);
        w.z = bf(st[kb][2]); w.w = bf(st[kb][3]);
        *reinterpret_cast<ushort4*>(&Pw[l15*72 + kb*16 + u*4]) = w;
      }
      ls += __shfl_xor(ls, 16);
      ls += __shfl_xor(ls, 32);
      lrun += ls;
    }

    // ---- O += P @ V  (A rows = q-rows from Plds, B cols = d from Vt) ----
    __builtin_amdgcn_s_setprio(1);
#pragma unroll
    for (int kc = 0; kc < 2; kc++){
      bf16x8 pa = *reinterpret_cast<const bf16x8*>(&Pw[l15*72 + kc*32 + u*8]);
#pragma unroll
      for (int d0 = 0; d0 < 4; d0++){
        const int vrow = d0*16 + l15;
        bf16x8 vb8 = *reinterpret_cast<const bf16x8*>(
            &Vb[vrow*64 + (((kc*4+u) ^ (vrow&7))*8)]);
        o[d0] = __builtin_amdgcn_mfma_f32_16x16x32_bf16(pa, vb8, o[d0], 0, 0, 0);
      }
    }
    __builtin_amdgcn_s_setprio(0);

    __syncthreads();  // publishes tile t+1 (vmcnt drain) + protects buffer reuse
  }

  // epilogue: redistribute 1/lrun (l15-domain) to O-rows (u*4+j) and store
  {
    float inv = 1.0f / lrun;
    float invo[4];
#pragma unroll
    for (int j = 0; j < 4; j++) invo[j] = __shfl(inv, u4j[j]);
#pragma unroll
    for (int d0 = 0; d0 < 4; d0++)
#pragma unroll
      for (int j = 0; j < 4; j++){
        float val = o[d0][j] * invo[j];
        ctx[(size_t)(q0 + u*4 + j)*2048 + h*64 + d0*16 + l15] = bf(val);
      }
  }
}

// ---------------- launcher ----------------
extern "C" void kernel_launch(void* const* d_in, const int* in_sizes, int n_in,
                              void* d_out, int out_size, void* d_ws, size_t ws_size,
                              hipStream_t stream){
  const float* x    = (const float*)d_in[0];
  // d_in[1] = mask (unused; causal mask computed analytically)
  const float* cosp = (const float*)d_in[2];
  const float* sinp = (const float*)d_in[3];
  const float* wq   = (const float*)d_in[4];
  const float* wk   = (const float*)d_in[5];
  const float* wv   = (const float*)d_in[6];
  const float* wo   = (const float*)d_in[7];
  const float* qg   = (const float*)d_in[8];
  const float* kg   = (const float*)d_in[9];
  float* out = (float*)d_out;

  char* ws = (char*)d_ws;
  ushort* xb   = (ushort*)(ws);                    //  8 MB  x bf16
  ushort* wcat = (ushort*)(ws + 8388608);          // 12 MB  [wq;wk;wv] bf16 [3072][2048]
  ushort* wob  = (ushort*)(ws + 20971520);         //  8 MB  wo bf16
  float*  qkvf = (float* )(ws + 29360128);         // 24 MB  qkv f32 [2048][3072]
  ushort* qbuf = (ushort*)(ws + 54525952);         //  8 MB  q bf16 [2048][2048] (pre-scaled)
  ushort* kbuf = (ushort*)(ws + 62914560);         //  2 MB  k bf16 [2048][512]
  ushort* vtb  = (ushort*)(ws + 65011712);         //  2 MB  v^T bf16 [8*64][2048]
  ushort* ctxb = (ushort*)(ws + 67108864);         //  8 MB  ctx bf16 [2048][2048]
  // total 75,497,472 bytes

  k_cvt<<<4096, 256, 0, stream>>>(x,  xb,  1048576);
  k_cvt<<<4096, 256, 0, stream>>>(wo, wob, 1048576);
  k_cvtw<<<6144, 256, 0, stream>>>(wq, wk, wv, wcat);

  k_gemm_bt<<<dim3(24, 16), 256, 0, stream>>>(xb, wcat, qkvf, 2048, 3072, 2048);
  k_normrope<<<2048, 256, 0, stream>>>(qkvf, cosp, sinp, qg, kg, qbuf, kbuf);
  k_vtrans<<<256, 256, 0, stream>>>(qkvf, vtb);
  k_attn<<<1024, 256, 0, stream>>>(qbuf, kbuf, vtb, ctxb);
  k_gemm_bt<<<dim3(16, 16), 256, 0, stream>>>(ctxb, wob, out, 2048, 2048, 2048);
}